// Round 6
// baseline (257.262 us; speedup 1.0000x reference)
//
#include <hip/hip_runtime.h>
#include <hip/hip_bf16.h>
#include <stdint.h>

// MMoE: E=16 experts, T=4 tasks, H=512, I=1024, B=8192.
// out[t,b] = sum_e g[b,t,e] * (sum_h relu(x@We^T+be)[b,e,h] * Wf[t,h]) + bf[t]
//
// R19: fuse cvt3 + logits into ONE prep kernel. moe_main is UNCHANGED from
// R18 (best measured: 142.0 us; five schedule variants R14-R18 all land
// 140-148 us / MfmaUtil 40-43% -> converged; 2-blocks/CU impossible:
// VGPR 128 + AGPR 128 = 256 regs/wave caps the 256^2 tile at 8 waves/CU).
// The remaining addressable time is OUTSIDE moe_main (~110 us total):
// cvt3 (~17-20 us, BW-bound) ran SERIALLY before logits (~20-30 us on only
// 64 blocks = 25% of CUs, latency-serial staging). They are independent if
// logits reads x/Wg fp32 and converts in-registers (each element read once,
// so pre-conversion buys logits nothing). Fused kernel: blocks 0..63 =
// logits (fp32 -> f2bf_rne in regs -> ds_write staging, double-buffered so
// HBM latency hides under the MFMA+softmax of the previous k-tile); blocks
// 64.. = cvt stream (x|We only; wgb eliminated). Saves the serialization +
// one launch gap.
// R13 invariant kept: moe blockIdx.x = mb -> disjoint out rows.

#define E_ 16
#define T_ 4
#define H_ 512
#define I_ 1024
#define B_ 8192
#define N_ (E_ * H_) /* 8192 */
#define K_ I_        /* 1024 */

typedef __bf16 bf16x8 __attribute__((ext_vector_type(8)));
typedef float f32x4 __attribute__((ext_vector_type(4)));

__device__ __forceinline__ unsigned short f2bf_rne(float f) {
  unsigned int b = __float_as_uint(f);
  b += 0x7fffu + ((b >> 16) & 1u);
  return (unsigned short)(b >> 16);
}

#define N4X (B_ * K_ / 4) /* 2097152 */
#define N4W (N_ * K_ / 4) /* 2097152 */

__device__ __forceinline__ void gld_lds16(const void* gp, void* lp) {
  __builtin_amdgcn_global_load_lds((const __attribute__((address_space(1))) void*)gp,
                                   (__attribute__((address_space(3))) void*)lp, 16, 0, 0);
}

// ---------------- fused prep kernel ----------------
// blocks [0,64): logits+softmax for m0 = blockIdx.x*128 (reads x/Wg fp32,
//   converts in-registers, stages bf16 to LDS double-buffer, MFMA, softmax
//   over experts, writes g[B][64]).
// blocks [64,..): fp32->bf16 stream cvt of x|We; first T_*B_ threads also
//   init out[t*B+b] = bf[t] (atomic-accumulated by moe_main; harness
//   re-poisons out before every launch).
__global__ __launch_bounds__(256) void prep_kernel(
    const float* __restrict__ x,    // [B_][K_] fp32
    const float* __restrict__ Wg,   // [64][K_] fp32 (T*E flattened)
    const float* __restrict__ bg,   // [64]
    const float* __restrict__ We,   // [N_][K_] fp32
    const float* __restrict__ bfv,  // [T_]
    unsigned short* __restrict__ xb,
    unsigned short* __restrict__ wb,
    float* __restrict__ g,          // [B_][64]
    float* __restrict__ out)        // [T_][B_]
{
  const int tid = threadIdx.x;

  if (blockIdx.x >= 64) {
    // ---- cvt part ----
    int i = (blockIdx.x - 64) * 256 + tid;
    if (i < T_ * B_) out[i] = bfv[i >> 13];  // t = i / 8192
    const float* src;
    unsigned short* dst;
    int j;
    if (i < N4X) {
      src = x; dst = xb; j = i;
    } else if (i < N4X + N4W) {
      src = We; dst = wb; j = i - N4X;
    } else {
      return;
    }
    float4 v = reinterpret_cast<const float4*>(src)[j];
    ushort4 o;
    o.x = f2bf_rne(v.x);
    o.y = f2bf_rne(v.y);
    o.z = f2bf_rne(v.z);
    o.w = f2bf_rne(v.w);
    reinterpret_cast<ushort4*>(dst)[j] = o;
    return;
  }

  // ---- logits part ----
  // LDS layout per buffer: rows of 32 bf16 (64 B), 4 16B-slots; chunk c of
  // row r stored at slot c ^ ((r>>1)&3)  (same swizzle the MFMA reads use).
  __shared__ struct {
    unsigned short A[2][128 * 32];  // 2 x 8 KB
    unsigned short B[2][64 * 32];   // 2 x 4 KB
  } st;

  const int w = tid >> 6, l = tid & 63;
  const int m16 = l & 15, q = l >> 4;
  const size_t m0 = (size_t)blockIdx.x * 128;

  // staging: thread covers A-row ra = tid>>1, k-half kh = tid&1 (16 floats);
  // threads < 128 additionally cover B-row rb = tid>>1 (16 floats).
  const int ra = tid >> 1, kh = tid & 1;
  const float* xrow = x + (m0 + ra) * K_ + kh * 16;
  const float* grow = Wg + (size_t)ra * K_ + kh * 16;  // valid when tid < 128
  const int swA0 = ((kh * 2 + 0) ^ ((ra >> 1) & 3)) * 8;
  const int swA1 = ((kh * 2 + 1) ^ ((ra >> 1) & 3)) * 8;

  // MFMA fragment read addressing (same as verified logits kernel)
  const int arow = w * 32 + m16;
  const int sA = q ^ ((arow >> 1) & 3);
  const int sB = q ^ ((m16 >> 1) & 3);

  float4 apf0, apf1, apf2, apf3, bpf0, bpf1, bpf2, bpf3;
#define LOADREG(kt_)                                                    \
  do {                                                                  \
    const float4* xp = reinterpret_cast<const float4*>(xrow + (kt_) * 32); \
    apf0 = xp[0]; apf1 = xp[1]; apf2 = xp[2]; apf3 = xp[3];             \
    if (tid < 128) {                                                    \
      const float4* gp = reinterpret_cast<const float4*>(grow + (kt_) * 32); \
      bpf0 = gp[0]; bpf1 = gp[1]; bpf2 = gp[2]; bpf3 = gp[3];           \
    }                                                                   \
  } while (0)

#define PACK8(dst_, va_, vb_)                                           \
  do {                                                                  \
    union { ushort u[8]; uint4 v; } pk_;                                \
    pk_.u[0] = f2bf_rne(va_.x); pk_.u[1] = f2bf_rne(va_.y);             \
    pk_.u[2] = f2bf_rne(va_.z); pk_.u[3] = f2bf_rne(va_.w);             \
    pk_.u[4] = f2bf_rne(vb_.x); pk_.u[5] = f2bf_rne(vb_.y);             \
    pk_.u[6] = f2bf_rne(vb_.z); pk_.u[7] = f2bf_rne(vb_.w);             \
    *reinterpret_cast<uint4*>(dst_) = pk_.v;                            \
  } while (0)

#define WRITE_LDS(pb_)                                                  \
  do {                                                                  \
    PACK8(st.A[pb_] + ra * 32 + swA0, apf0, apf1);                      \
    PACK8(st.A[pb_] + ra * 32 + swA1, apf2, apf3);                      \
    if (tid < 128) {                                                    \
      PACK8(st.B[pb_] + ra * 32 + swA0, bpf0, bpf1);                    \
      PACK8(st.B[pb_] + ra * 32 + swA1, bpf2, bpf3);                    \
    }                                                                   \
  } while (0)

  f32x4 acc[2][4] = {};

  LOADREG(0);
#pragma unroll 1
  for (int kt = 0; kt < 32; ++kt) {
    const int pb = kt & 1;
    __syncthreads();  // buf pb free (its readers, k-tile kt-2, are done)
    WRITE_LDS(pb);
    if (kt < 31) LOADREG(kt + 1);  // prefetch: HBM latency hides under MFMA
    __syncthreads();  // writes visible
    bf16x8 af[2], bfr[4];
#pragma unroll
    for (int i = 0; i < 2; ++i)
      af[i] = *reinterpret_cast<const bf16x8*>(st.A[pb] + (arow + i * 16) * 32 + sA * 8);
#pragma unroll
    for (int j = 0; j < 4; ++j)
      bfr[j] = *reinterpret_cast<const bf16x8*>(st.B[pb] + (j * 16 + m16) * 32 + sB * 8);
#pragma unroll
    for (int i = 0; i < 2; ++i)
#pragma unroll
      for (int j = 0; j < 4; ++j)
        acc[i][j] = __builtin_amdgcn_mfma_f32_16x16x32_bf16(af[i], bfr[j], acc[i][j], 0, 0, 0);
  }

  // acc[i][j][r] = L[row = w*32+16i+4q+r][te = j*16+m16]; t = j, e = m16.
  float bgv[4];
#pragma unroll
  for (int j = 0; j < 4; ++j) bgv[j] = bg[j * 16 + m16];

#pragma unroll
  for (int i = 0; i < 2; ++i) {
    float lg[4][4];  // [r][j]
#pragma unroll
    for (int j = 0; j < 4; ++j)
#pragma unroll
      for (int r = 0; r < 4; ++r) lg[r][j] = acc[i][j][r] + bgv[j];
#pragma unroll
    for (int r = 0; r < 4; ++r) {
#pragma unroll
      for (int j = 0; j < 4; ++j) {
        float m = lg[r][j];
#pragma unroll
        for (int mask = 1; mask < 16; mask <<= 1) m = fmaxf(m, __shfl_xor(m, mask, 64));
        float ex = __expf(lg[r][j] - m);
        float s = ex;
#pragma unroll
        for (int mask = 1; mask < 16; mask <<= 1) s += __shfl_xor(s, mask, 64);
        size_t b = m0 + w * 32 + i * 16 + q * 4 + r;
        g[b * 64 + j * 16 + m16] = ex / s;
      }
    }
  }
}

// -- 256^2 single-barrier 4-ring, reg-dbuf, COUNTED-lgkm main (R18, best) --

extern __shared__ char smem[];  // 131072 B: ring buf b at b*32768; A +0, B +16384

#define BARRIER()                          \
  do {                                     \
    asm volatile("" ::: "memory");         \
    __builtin_amdgcn_s_barrier();          \
    asm volatile("" ::: "memory");         \
  } while (0)
#define VMW(n) asm volatile("s_waitcnt vmcnt(" #n ")" ::: "memory")
#define LGKM(n) asm volatile("s_waitcnt lgkmcnt(" #n ")" ::: "memory")
#define SCHED0() __builtin_amdgcn_sched_barrier(0)

#define STAGE4(t_)                                                             \
  do {                                                                         \
    const int bb_ = ((t_) & 3) * 32768;                                        \
    const int ko_ = (t_) * 32;                                                 \
    gld_lds16(A + baseAg + ko_, smem + bb_ + ldsW);                            \
    gld_lds16(A + baseAg + 16 * K_ + ko_, smem + bb_ + ldsW + 1024);           \
    gld_lds16(Bm + baseBg + ko_, smem + bb_ + 16384 + ldsW);                   \
    gld_lds16(Bm + baseBg + 16 * K_ + ko_, smem + bb_ + 16384 + ldsW + 1024);  \
  } while (0)

#define READF(S, t_)                                                                      \
  do {                                                                                    \
    const int bb_ = ((t_) & 3) * 32768;                                                   \
    _Pragma("unroll") for (int i = 0; i < 8; ++i) af##S[i] =                              \
        *reinterpret_cast<const bf16x8*>(smem + bb_ + baseA_rd + i * 1024 + sl16);        \
    _Pragma("unroll") for (int j = 0; j < 4; ++j) bfr##S[j] =                             \
        *reinterpret_cast<const bf16x8*>(smem + bb_ + 16384 + baseB_rd + j * 1024 + sl16);\
  } while (0)

#define MFMA32(S)                                                                         \
  do {                                                                                    \
    __builtin_amdgcn_s_setprio(1);                                                        \
    _Pragma("unroll") for (int i = 0; i < 8; ++i)                                         \
        _Pragma("unroll") for (int j = 0; j < 4; ++j)                                     \
            acc[i][j] = __builtin_amdgcn_mfma_f32_16x16x32_bf16(af##S[i], bfr##S[j],      \
                                                                acc[i][j], 0, 0, 0);      \
    __builtin_amdgcn_s_setprio(0);                                                        \
    SCHED0();                                                                             \
  } while (0)

__global__ __launch_bounds__(512, 2) void moe_main_kernel(
    const unsigned short* __restrict__ A,   // x bf16 [B_][K_]
    const unsigned short* __restrict__ Bm,  // We bf16 [N_][K_]
    const float* __restrict__ be,           // [E_*H_] flat == indexed by n
    const float* __restrict__ Wf,           // [T_][H_]
    const float* __restrict__ g,            // [B_][64] (t*16+e)
    float* __restrict__ out)                // [T_][B_] (pre-init to bf[t])
{
  const int tid = threadIdx.x;
  const int w = tid >> 6, l = tid & 63;
  const int wm = w >> 2, wn = w & 3;  // 2 M-waves x 4 N-waves; wave tile 128x64
  const int m16 = l & 15, q = l >> 4;
  const int mb = blockIdx.x, nb = blockIdx.y;  // x=mb: decorrelate atomics (R13)
  const size_t m0 = (size_t)mb * 256, n0 = (size_t)nb * 256;

  const int c8 = (((l & 3) ^ ((l >> 3) & 3)) * 8);
  const size_t baseAg = (m0 + w * 32 + (l >> 2)) * K_ + c8;
  const size_t baseBg = (n0 + w * 32 + (l >> 2)) * K_ + c8;
  const int ldsW = w * 2048;  // (w*32 rows) * 64 B

  const int sl16 = (q ^ ((m16 >> 1) & 3)) * 16;
  const int baseA_rd = (wm * 128 + m16) * 64;
  const int baseB_rd = (wn * 64 + m16) * 64;

  f32x4 acc[8][4] = {};
  bf16x8 afA[8], bfrA[4], afB[8], bfrB[4];

  STAGE4(0);
  STAGE4(1);
  STAGE4(2);
  VMW(8);
  BARRIER();
  READF(A, 0);

#pragma unroll 1
  for (int t = 0; t < 28; t += 2) {
    VMW(4);
    BARRIER();
    LGKM(12);
    STAGE4(t + 3);
    READF(B, t + 1);
    LGKM(12);
    SCHED0();
    MFMA32(A);

    VMW(4);
    BARRIER();
    LGKM(12);
    STAGE4(t + 4);
    READF(A, t + 2);
    LGKM(12);
    SCHED0();
    MFMA32(B);
  }
  VMW(4);
  BARRIER();
  LGKM(12);
  STAGE4(31);
  READF(B, 29);
  LGKM(12);
  SCHED0();
  MFMA32(A);
  VMW(4);
  BARRIER();
  READF(A, 30);
  LGKM(12);
  SCHED0();
  MFMA32(B);
  VMW(0);
  BARRIER();
  READF(B, 31);
  LGKM(12);
  SCHED0();
  MFMA32(A);
  LGKM(0);
  SCHED0();
  MFMA32(B);

  __syncthreads();  // staging LDS dead; reuse as allsums[4][1024] floats

  // ---- epilogue: relu+bias, Wf contraction, butterfly, cross-wn combine ----
  float* allsums = (float*)smem;

  const int hb = (int)(n0 & 511);
  const int e_idx = (int)(n0 >> 9);

  float wfv[4][4];  // [t][j]
#pragma unroll
  for (int t = 0; t < 4; ++t)
#pragma unroll
    for (int j = 0; j < 4; ++j)
      wfv[t][j] = Wf[t * H_ + hb + wn * 64 + j * 16 + m16];
  float bias[4];
#pragma unroll
  for (int j = 0; j < 4; ++j) bias[j] = be[n0 + wn * 64 + j * 16 + m16];

  const int b0s = m16 & 1, b1s = (m16 >> 1) & 1, b2s = (m16 >> 2) & 1, b3s = (m16 >> 3) & 1;
#pragma unroll
  for (int i = 0; i < 8; ++i) {
    float eo[4][4];  // [j][reg]
#pragma unroll
    for (int j = 0; j < 4; ++j)
#pragma unroll
      for (int r = 0; r < 4; ++r) eo[j][r] = fmaxf(acc[i][j][r] + bias[j], 0.f);
    float p[16];  // slot s = reg*4 + t
#pragma unroll
    for (int r = 0; r < 4; ++r)
#pragma unroll
      for (int t = 0; t < 4; ++t) {
        float v = 0.f;
#pragma unroll
        for (int j = 0; j < 4; ++j) v += eo[j][r] * wfv[t][j];
        p[r * 4 + t] = v;
      }
    float q8[8];
#pragma unroll
    for (int m = 0; m < 8; ++m) {
      float sent = b0s ? p[2 * m] : p[2 * m + 1];
      float recv = __shfl_xor(sent, 1, 64);
      q8[m] = (b0s ? p[2 * m + 1] : p[2 * m]) + recv;
    }
    float q4[4];
#pragma unroll
    for (int u = 0; u < 4; ++u) {
      float sent = b1s ? q8[2 * u] : q8[2 * u + 1];
      float recv = __shfl_xor(sent, 2, 64);
      q4[u] = (b1s ? q8[2 * u + 1] : q8[2 * u]) + recv;
    }
    float q2[2];
#pragma unroll
    for (int u = 0; u < 2; ++u) {
      float sent = b2s ? q4[2 * u] : q4[2 * u + 1];
      float recv = __shfl_xor(sent, 4, 64);
      q2[u] = (b2s ? q4[2 * u + 1] : q4[2 * u]) + recv;
    }
    float sent = b3s ? q2[0] : q2[1];
    float recv = __shfl_xor(sent, 8, 64);
    float v = (b3s ? q2[1] : q2[0]) + recv;  // slot == m16

    int row = wm * 128 + i * 16 + q * 4 + (m16 >> 2);
    allsums[wn * 1024 + row * 4 + (m16 & 3)] = v;
  }
  __syncthreads();

  {
    float2 s = *reinterpret_cast<float2*>(&allsums[0 * 1024 + tid * 2]);
    float2 x1 = *reinterpret_cast<float2*>(&allsums[1 * 1024 + tid * 2]);
    float2 x2 = *reinterpret_cast<float2*>(&allsums[2 * 1024 + tid * 2]);
    float2 x3 = *reinterpret_cast<float2*>(&allsums[3 * 1024 + tid * 2]);
    s.x += x1.x + x2.x + x3.x;
    s.y += x1.y + x2.y + x3.y;
#pragma unroll
    for (int oi = 0; oi < 2; ++oi) {
      int o = tid * 2 + oi;  // 1024 = 256 rows x 4 t
      int row = o >> 2, t = o & 3;
      float sv = oi ? s.y : s.x;
      size_t b = m0 + row;
      float gv = g[b * 64 + t * 16 + e_idx];
      atomicAdd(&out[(size_t)t * B_ + b], gv * sv);
    }
  }
}

extern "C" void kernel_launch(void* const* d_in, const int* in_sizes, int n_in,
                              void* d_out, int out_size, void* d_ws, size_t ws_size,
                              hipStream_t stream) {
  const float* x = (const float*)d_in[0];   // [B, I]
  const float* We = (const float*)d_in[1];  // [E, H, I]
  const float* be = (const float*)d_in[2];  // [E, H]
  const float* Wg = (const float*)d_in[3];  // [T, E, I]
  const float* bg = (const float*)d_in[4];  // [T, E]
  const float* Wf = (const float*)d_in[5];  // [T, H]
  const float* bf = (const float*)d_in[6];  // [T]
  float* out = (float*)d_out;               // [T, B, 1]

  // ws: xb (16.8MB) | wb (16.8MB) | g (2.1MB)   (wgb eliminated)
  unsigned short* xb = (unsigned short*)d_ws;
  unsigned short* wb = xb + (size_t)B_ * K_;
  float* g = (float*)(wb + (size_t)N_ * K_);

  // opt-in for 128 KiB dynamic LDS (host-side, not a stream op: capture-safe)
  hipFuncSetAttribute((const void*)moe_main_kernel,
                      hipFuncAttributeMaxDynamicSharedMemorySize, 131072);

  // 64 logits blocks (dispatched first, long-pole) + 16384 cvt blocks
  prep_kernel<<<64 + (N4X + N4W) / 256, 256, 0, stream>>>(x, Wg, bg, We, bf, xb, wb, g, out);
  dim3 grid(B_ / 256, N_ / 256);  // x = mb (disjoint out rows among concurrent blocks)
  moe_main_kernel<<<grid, 512, 131072, stream>>>(xb, wb, be, Wf, g, out);
}